// Round 5
// baseline (555.309 us; speedup 1.0000x reference)
//
#include <hip/hip_runtime.h>
#include <stdint.h>

#define BB 4
#define SS 2048
#define HIDW 2048
#define NH 16
#define NKV 4
#define DD 128
#define KVB 32

typedef unsigned short u16;
typedef unsigned long long u64;
typedef unsigned int uint;
typedef __attribute__((ext_vector_type(8))) short bf16x8;
typedef __attribute__((ext_vector_type(4))) float f32x4;
typedef __attribute__((ext_vector_type(2))) float f32x2;
typedef __attribute__((ext_vector_type(2))) __bf16 bf16x2;

__device__ __forceinline__ u16 f2bf1(float f) {
  __bf16 h = (__bf16)f;
  return __builtin_bit_cast(u16, h);
}

__device__ __forceinline__ float bf2f(u16 v) {
  return __uint_as_float((uint)v << 16);
}

// packed f32 pair -> bf16 pair (v_cvt_pk_bf16_f32 on gfx950)
__device__ __forceinline__ uint pkbf(float a, float b) {
  f32x2 v = {a, b};
  bf16x2 h = __builtin_convertvector(v, bf16x2);
  return __builtin_bit_cast(uint, h);
}

__device__ __forceinline__ void gld_lds16(const void* g, void* s) {
  __builtin_amdgcn_global_load_lds(
      (const __attribute__((address_space(1))) void*)g,
      (__attribute__((address_space(3))) void*)(unsigned)(uintptr_t)s,
      16, 0, 0);
}

#define VMCNT(n) asm volatile("s_waitcnt vmcnt(" #n ")" ::: "memory")

__device__ __forceinline__ void barx() {
  asm volatile("" ::: "memory");
  __builtin_amdgcn_s_barrier();
  asm volatile("" ::: "memory");
}

// ---------------- fp32 -> bf16 cast (x) ----------------
__global__ __launch_bounds__(256) void cast_f32_bf16(const float* __restrict__ in,
                                                     u16* __restrict__ out, int n4) {
  int i = blockIdx.x * 256 + threadIdx.x;
  if (i < n4) {
    float4 f = ((const float4*)in)[i];
    uint2 o;
    o.x = pkbf(f.x, f.y);
    o.y = pkbf(f.z, f.w);
    ((uint2*)out)[i] = o;
  }
}

// ---------------- all 4 weight casts in one launch ----------------
__global__ __launch_bounds__(256) void cast_weights(const float* __restrict__ wq,
                                                    const float* __restrict__ wk,
                                                    const float* __restrict__ wv,
                                                    const float* __restrict__ wo,
                                                    u16* __restrict__ wqkvb,
                                                    u16* __restrict__ wob) {
  int i = blockIdx.x * 256 + threadIdx.x;
  const float* src;
  uint2* dst;
  int off;
  if (i < 1048576) {
    src = wq; dst = (uint2*)wqkvb; off = i;
  } else if (i < 1310720) {
    src = wk; dst = (uint2*)(wqkvb + (size_t)2048 * 2048); off = i - 1048576;
  } else if (i < 1572864) {
    src = wv; dst = (uint2*)(wqkvb + (size_t)2560 * 2048); off = i - 1310720;
  } else {
    src = wo; dst = (uint2*)wob; off = i - 1572864;
  }
  float4 f = ((const float4*)src)[off];
  uint2 o;
  o.x = pkbf(f.x, f.y);
  o.y = pkbf(f.z, f.w);
  dst[off] = o;
}

// ---------------- 256x256 8-wave 4-phase pipelined GEMM mainloop ----------------
// (unchanged from R1/R4, proven)
__device__ __forceinline__ void mm256(const u16* __restrict__ A,
                                      const u16* __restrict__ Bt,
                                      int row0, int col0, f32x4 (&acc)[4][8]) {
  __shared__ u16 S[2][2][16384];
  const int tid = threadIdx.x;
  const int wave = tid >> 6, lane = tid & 63;
  const int lr = lane & 15, lq = lane >> 4;
  const int wr = wave >> 1, wc = wave & 1;

  const int sk = ((tid & 7) * 8) ^ (((tid >> 5) & 1) << 4);
  const u16* aS = A + (size_t)(row0 + (tid >> 3)) * 2048 + sk;
  const u16* bS = Bt + (size_t)(col0 + (tid >> 3)) * 2048 + sk;

  const int rsw = (lq * 16) ^ (((lr >> 2) & 1) << 5);
  const int aoff = (wr * 64 + lr) * 128 + rsw;
  const int boff = (wc * 128 + lr) * 128 + rsw;

  auto stA = [&](int buf, int h, int k0) {
    char* d = (char*)&S[buf][0][0] + h * 16384 + wave * 1024;
    const u16* s = aS + (size_t)h * 262144 + k0;
    gld_lds16(s, d);
    gld_lds16(s + 131072, d + 8192);
  };
  auto stB = [&](int buf, int h, int k0) {
    char* d = (char*)&S[buf][1][0] + h * 16384 + wave * 1024;
    const u16* s = bS + (size_t)h * 262144 + k0;
    gld_lds16(s, d);
    gld_lds16(s + 131072, d + 8192);
  };

  stA(0, 0, 0);
  stA(0, 1, 0);
  stB(0, 0, 0);
  stB(0, 1, 0);

  for (int t = 0; t < 32; ++t) {
    const int cur = t & 1;
    const char* LA = (const char*)&S[cur][0][0];
    const char* LB = (const char*)&S[cur][1][0];
    const int nk0 = (t + 1) * 64;

    if (t < 31) {
      stA(cur ^ 1, 0, nk0);
      stA(cur ^ 1, 1, nk0);
      VMCNT(4);
    } else {
      VMCNT(0);
    }
    barx();

    bf16x8 a0[2][2], a1[2][2], bq[4][2];
    // ---- ph0 ----
#pragma unroll
    for (int m2 = 0; m2 < 2; ++m2)
#pragma unroll
      for (int kk = 0; kk < 2; ++kk)
        a0[m2][kk] = *(const bf16x8*)(LA + aoff + m2 * 2048 + kk * 64);
#pragma unroll
    for (int n = 0; n < 4; ++n)
#pragma unroll
      for (int kk = 0; kk < 2; ++kk)
        bq[n][kk] = *(const bf16x8*)(LB + boff + n * 2048 + kk * 64);
    if (t < 31) stB(cur ^ 1, 0, nk0);
    barx();
    __builtin_amdgcn_s_setprio(1);
#pragma unroll
    for (int kk = 0; kk < 2; ++kk)
#pragma unroll
      for (int m2 = 0; m2 < 2; ++m2)
#pragma unroll
        for (int n = 0; n < 4; ++n)
          acc[m2][n] = __builtin_amdgcn_mfma_f32_16x16x32_bf16(a0[m2][kk], bq[n][kk],
                                                               acc[m2][n], 0, 0, 0);
    __builtin_amdgcn_s_setprio(0);
    barx();

    // ---- ph1 ----
#pragma unroll
    for (int m2 = 0; m2 < 2; ++m2)
#pragma unroll
      for (int kk = 0; kk < 2; ++kk)
        a1[m2][kk] = *(const bf16x8*)(LA + aoff + (m2 + 2) * 2048 + kk * 64);
    if (t < 31) stB(cur ^ 1, 1, nk0);
    barx();
    __builtin_amdgcn_s_setprio(1);
#pragma unroll
    for (int kk = 0; kk < 2; ++kk)
#pragma unroll
      for (int m2 = 0; m2 < 2; ++m2)
#pragma unroll
        for (int n = 0; n < 4; ++n)
          acc[m2 + 2][n] = __builtin_amdgcn_mfma_f32_16x16x32_bf16(a1[m2][kk], bq[n][kk],
                                                                   acc[m2 + 2][n], 0, 0, 0);
    __builtin_amdgcn_s_setprio(0);
    barx();

    // ---- ph2 ----
#pragma unroll
    for (int n = 0; n < 4; ++n)
#pragma unroll
      for (int kk = 0; kk < 2; ++kk)
        bq[n][kk] = *(const bf16x8*)(LB + boff + (n + 4) * 2048 + kk * 64);
    barx();
    __builtin_amdgcn_s_setprio(1);
#pragma unroll
    for (int kk = 0; kk < 2; ++kk)
#pragma unroll
      for (int m2 = 0; m2 < 2; ++m2)
#pragma unroll
        for (int n = 0; n < 4; ++n)
          acc[m2 + 2][n + 4] = __builtin_amdgcn_mfma_f32_16x16x32_bf16(
              a1[m2][kk], bq[n][kk], acc[m2 + 2][n + 4], 0, 0, 0);
    __builtin_amdgcn_s_setprio(0);
    barx();

    // ---- ph3 ----
    __builtin_amdgcn_s_setprio(1);
#pragma unroll
    for (int kk = 0; kk < 2; ++kk)
#pragma unroll
      for (int m2 = 0; m2 < 2; ++m2)
#pragma unroll
        for (int n = 0; n < 4; ++n)
          acc[m2][n + 4] = __builtin_amdgcn_mfma_f32_16x16x32_bf16(
              a0[m2][kk], bq[n][kk], acc[m2][n + 4], 0, 0, 0);
    __builtin_amdgcn_s_setprio(0);
    barx();
  }
}

// ---------------- fused QKV GEMM + RoPE + head scatter + V transpose -----------
__global__ __launch_bounds__(512, 2) void gemm_qkv_rope256(const u16* __restrict__ A,
                                                           const u16* __restrict__ Bt,
                                                           const float* __restrict__ cosT,
                                                           const float* __restrict__ sinT,
                                                           u16* __restrict__ qb,
                                                           u16* __restrict__ kb,
                                                           u16* __restrict__ vt) {
  const int bid = blockIdx.x;                 // 384 blocks, 384%8==0
  const int nid = (bid & 7) * 48 + (bid >> 3);  // XCD-chunked, y-major per XCD
  const int bxx = nid % 12, byy = nid / 12;
  const int row0 = byy * 256, col0 = bxx * 256;

  f32x4 acc[4][8] = {};
  mm256(A, Bt, row0, col0, acc);

  const int tid = threadIdx.x;
  const int wave = tid >> 6, lane = tid & 63;
  const int lr = lane & 15, lq = lane >> 4;
  const int wr = wave >> 1, wc = wave & 1;

  const int b_ = row0 >> 11;                 // tile never crosses batch (2048%256==0)
  const int sbase = (row0 & (SS - 1)) + wr * 64;
  const int hsel = bxx * 2 + wc;             // wave covers exactly one 128-wide head

  if (hsel < 20) {
    // q-heads: fold 1/sqrt(D) * log2(e) so flash can use exp2 directly
    const float scale = (hsel < 16) ? 0.12751744416168222f : 1.0f;
    u16* base = (hsel < 16)
                    ? qb + (size_t)(b_ * NH + hsel) * SS * DD
                    : kb + (size_t)(b_ * NKV + (hsel - 16)) * SS * DD;
#pragma unroll
    for (int i = 0; i < 4; i++) {
#pragma unroll
      for (int r = 0; r < 4; r++) {
        int s = sbase + i * 16 + lq * 4 + r;
        const float* cp = cosT + (size_t)s * DD;
        const float* sp = sinT + (size_t)s * DD;
        u16* drow = base + (size_t)s * DD;
#pragma unroll
        for (int j = 0; j < 4; j++) {
          int d = j * 16 + lr;
          float c = cp[d], si = sp[d];
          float x0 = acc[i][j][r] * scale, x1 = acc[i][j + 4][r] * scale;
          drow[d] = f2bf1(x0 * c - x1 * si);
          drow[d + 64] = f2bf1(x1 * c + x0 * si);
        }
      }
    }
  } else {
    const int kv = hsel - 20;
#pragma unroll
    for (int i = 0; i < 4; i++) {
      int s = sbase + i * 16 + lq * 4;
#pragma unroll
      for (int j = 0; j < 8; j++) {
        int d = j * 16 + lr;
        u64 pw = (u64)pkbf(acc[i][j][0], acc[i][j][1]) |
                 ((u64)pkbf(acc[i][j][2], acc[i][j][3]) << 32);
        *(u64*)(vt + (size_t)((b_ * NKV + kv) * DD + d) * SS + s) = pw;
      }
    }
  }
}

// ---------------- out-projection GEMM: out(f32) = ob(bf16) * wob^T --------------
__global__ __launch_bounds__(512, 2) void gemm_out256(const u16* __restrict__ A,
                                                      const u16* __restrict__ Bt,
                                                      float* __restrict__ C) {
  const int bid = blockIdx.x;                 // 256 blocks
  const int nid = (bid & 7) * 32 + (bid >> 3);
  const int bxx = nid & 7, byy = nid >> 3;
  const int row0 = byy * 256, col0 = bxx * 256;

  f32x4 acc[4][8] = {};
  mm256(A, Bt, row0, col0, acc);

  const int tid = threadIdx.x;
  const int wave = tid >> 6, lane = tid & 63;
  const int lr = lane & 15, lq = lane >> 4;
  const int wr = wave >> 1, wc = wave & 1;

#pragma unroll
  for (int i = 0; i < 4; i++) {
    int row = row0 + wr * 64 + i * 16 + lq * 4;
#pragma unroll
    for (int j = 0; j < 8; j++) {
      int col = col0 + wc * 128 + j * 16 + lr;
      float* cp = C + (size_t)row * HIDW + col;
#pragma unroll
      for (int r = 0; r < 4; r++) cp[(size_t)r * HIDW] = acc[i][j][r];
    }
  }
}

// ---------------- transposed flash attention v6: KVB=32, 4 blocks/CU ------------
// Same proven v4 dataflow (Pt round-trip), tiles halved in the kv dimension:
// LDS 40KB (Ks 2x8K + Vs 2x8K + Pt 8K) -> 4 blocks/CU (16 waves, 4/SIMD) to
// cover the QK->softmax->Pt->PV serialization with TLP. Softmax uses exp2
// (log2e pre-folded into Q's scale by the qkv epilogue). V/Pt rows are 64B;
// bank keys use the 4-bit-row double-key (r&3)^((r>>2)&3) to keep ~2-way max.
__global__ __launch_bounds__(256, 4) void flash_attn(const u16* __restrict__ qb,
                                                     const u16* __restrict__ kb,
                                                     const u16* __restrict__ vt,
                                                     u16* __restrict__ ob) {
  __shared__ u16 Ks[2][KVB * 128];  // [kv][d], 16B-blk swizzle ^ (row&15)
  __shared__ u16 Vs[2][128 * KVB];  // [d][s],  16B-blk swizzle ^ key(row)
  __shared__ u16 Pt[128 * KVB];     // [q][kv], 16B-blk swizzle ^ key(row)
  const int tid = threadIdx.x;
  const int wave = tid >> 6, lane = tid & 63;
  const int lr = lane & 15, lq = lane >> 4;

  const int lin = blockIdx.y * 16 + blockIdx.x;
  const int xcd = lin & 7;
  const int slot = lin >> 3;               // 0..127
  const int pr = xcd + ((slot & 1) << 3);  // (b,kvh) id 0..15
  const int b = pr >> 2, kvh = pr & 3;
  const int rest = slot >> 1;              // 0..63
  const int h = kvh * 4 + (rest & 3);
  const int q0 = (rest >> 2) * 128;
  const int bh = b * 16 + h;

  const size_t kbase = (size_t)(b * NKV + kvh) * SS * DD;
  const size_t vbase = (size_t)(b * NKV + kvh) * DD * SS;

  bf16x8 qf[2][4];
#pragma unroll
  for (int nt = 0; nt < 2; nt++) {
    const u16* qrow = qb + ((size_t)bh * SS + q0 + wave * 32 + nt * 16 + lr) * DD + lq * 8;
#pragma unroll
    for (int kk = 0; kk < 4; kk++) qf[nt][kk] = *(const bf16x8*)(qrow + kk * 32);
  }

  f32x4 o_acc[8][2] = {};
  float l_i[2] = {0.0f, 0.0f};

  // K staging: stored row (16/round) = c*16 + (tid>>4), swizzle key = row&15
  const int ktrow = tid >> 4;
  const int ktblk = (tid & 15) ^ ktrow;
  const u16* ksrc = kb + kbase + (size_t)ktrow * DD + ktblk * 8;
  // V staging: 64B rows (32 s); stored row (64/round) = c*64 + (tid>>2),
  // swizzle key = (row&3)^((row>>2)&3)  (c*64 and c*16 drop out of both keys)
  const int vtrow = tid >> 2;
  const int vtblk = (tid & 3) ^ (vtrow & 3) ^ ((vtrow >> 2) & 3);
  const u16* vsrc = vt + vbase + (size_t)vtrow * SS + vtblk * 8;

  // prologue: prefetch tile 0 into buffer 0
  {
    char* kd = (char*)(Ks[0]) + wave * 1024;
    char* vd = (char*)(Vs[0]) + wave * 1024;
#pragma unroll
    for (int c = 0; c < 2; c++) {
      gld_lds16(ksrc + (size_t)c * 16 * DD, kd + c * 4096);
      gld_lds16(vsrc + (size_t)c * 64 * SS, vd + c * 4096);
    }
  }

  const int pkey = (lr & 3) ^ ((lr >> 2) & 3);  // V-read & Pt key (lane-only)

  for (int it = 0; it < SS / KVB; it++) {
    __syncthreads();  // drains own prefetch (in flight for a whole compute phase)
    if (it + 1 < SS / KVB) {
      int s0 = (it + 1) * KVB;
      char* kd = (char*)(Ks[(it + 1) & 1]) + wave * 1024;
      char* vd = (char*)(Vs[(it + 1) & 1]) + wave * 1024;
#pragma unroll
      for (int c = 0; c < 2; c++) {
        gld_lds16(ksrc + (size_t)(s0 + c * 16) * DD, kd + c * 4096);
        gld_lds16(vsrc + s0 + (size_t)c * 64 * SS, vd + c * 4096);
      }
    }
    const u16* K = Ks[it & 1];
    const u16* V = Vs[it & 1];

    f32x4 sc[2][2] = {};
    __builtin_amdgcn_s_setprio(1);
#pragma unroll
    for (int kk = 0; kk < 4; kk++) {
#pragma unroll
      for (int mt = 0; mt < 2; mt++) {
        bf16x8 kf = *(const bf16x8*)(K + (mt * 16 + lr) * 128 + (((kk * 4 + lq) ^ lr) * 8));
#pragma unroll
        for (int nt = 0; nt < 2; nt++)
          sc[mt][nt] = __builtin_amdgcn_mfma_f32_16x16x32_bf16(kf, qf[nt][kk], sc[mt][nt], 0, 0, 0);
      }
    }
    __builtin_amdgcn_s_setprio(0);

#pragma unroll
    for (int nt = 0; nt < 2; nt++) {
      float rs = 0.0f;
#pragma unroll
      for (int mt = 0; mt < 2; mt++)
#pragma unroll
        for (int r = 0; r < 4; r++) {
          float p = __builtin_exp2f(sc[mt][nt][r]);  // log2e folded into Q scale
          sc[mt][nt][r] = p;
          rs += p;
        }
      l_i[nt] += rs;
      int prow = wave * 32 + nt * 16 + lr;
#pragma unroll
      for (int mt = 0; mt < 2; mt++) {
        u64 pw = (u64)pkbf(sc[mt][nt][0], sc[mt][nt][1]) |
                 ((u64)pkbf(sc[mt][nt][2], sc[mt][nt][3]) << 32);
        int bb = (mt * 2 + (lq >> 1)) ^ pkey;
        *(u64*)((char*)Pt + prow * 64 + bb * 16 + (lq & 1) * 8) = pw;
      }
    }

    __builtin_amdgcn_s_setprio(1);
    {
      bf16x8 pbf[2];
#pragma unroll
      for (int nt = 0; nt < 2; nt++) {
        int prow = wave * 32 + nt * 16 + lr;
        pbf[nt] = *(const bf16x8*)((char*)Pt + prow * 64 + ((lq ^ pkey) * 16));
      }
#pragma unroll
      for (int mt = 0; mt < 8; mt++) {
        bf16x8 vf = *(const bf16x8*)(V + (mt * 16 + lr) * KVB + ((lq ^ pkey) * 8));
#pragma unroll
        for (int nt = 0; nt < 2; nt++)
          o_acc[mt][nt] = __builtin_amdgcn_mfma_f32_16x16x32_bf16(vf, pbf[nt], o_acc[mt][nt], 0, 0, 0);
      }
    }
    __builtin_amdgcn_s_setprio(0);
  }

#pragma unroll
  for (int nt = 0; nt < 2; nt++) {
    float l = l_i[nt];
    l += __shfl_xor(l, 16, 64);
    l += __shfl_xor(l, 32, 64);
    float inv = 1.0f / l;
    size_t q = (size_t)q0 + wave * 32 + nt * 16 + lr;
    u16* dst = ob + ((size_t)b * SS + q) * HIDW + h * DD + lq * 4;
#pragma unroll
    for (int mt = 0; mt < 8; mt++) {
      uint2 pk;
      pk.x = pkbf(o_acc[mt][nt][0] * inv, o_acc[mt][nt][1] * inv);
      pk.y = pkbf(o_acc[mt][nt][2] * inv, o_acc[mt][nt][3] * inv);
      *(uint2*)(dst + mt * 16) = pk;
    }
  }
}

extern "C" void kernel_launch(void* const* d_in, const int* in_sizes, int n_in,
                              void* d_out, int out_size, void* d_ws, size_t ws_size,
                              hipStream_t stream) {
  const float* x = (const float*)d_in[0];
  const float* cosT = (const float*)d_in[1];
  const float* sinT = (const float*)d_in[2];
  const float* wq = (const float*)d_in[3];
  const float* wk = (const float*)d_in[4];
  const float* wv = (const float*)d_in[5];
  const float* wo = (const float*)d_in[6];
  float* out = (float*)d_out;

  char* ws = (char*)d_ws;
  size_t off = 0;
  auto alloc = [&](size_t bytes) {
    char* p = ws + off;
    off += (bytes + 255) & ~(size_t)255;
    return p;
  };
  const int M = BB * SS;
  u16* xb = (u16*)alloc((size_t)M * HIDW * 2);
  u16* wqkvb = (u16*)alloc((size_t)3072 * HIDW * 2);  // wq|wk|wv contiguous
  u16* wob = (u16*)alloc((size_t)HIDW * NH * DD * 2);
  u16* qb = (u16*)alloc((size_t)BB * NH * SS * DD * 2);
  u16* kb = (u16*)alloc((size_t)BB * NKV * SS * DD * 2);
  u16* vt = (u16*)alloc((size_t)BB * NKV * DD * SS * 2);
  u16* ob = (u16*)alloc((size_t)M * HIDW * 2);

  cast_f32_bf16<<<(M * HIDW) / 1024, 256, 0, stream>>>(x, xb, (M * HIDW) / 4);
  cast_weights<<<10240, 256, 0, stream>>>(wq, wk, wv, wo, wqkvb, wob);

  gemm_qkv_rope256<<<384, 512, 0, stream>>>(xb, wqkvb, cosT, sinT, qb, kb, vt);

  flash_attn<<<dim3(SS / 128, BB * NH), 256, 0, stream>>>(qb, kb, vt, ob);

  gemm_out256<<<256, 512, 0, stream>>>(ob, wob, out);
}

// Round 6
// 493.958 us; speedup vs baseline: 1.1242x; 1.1242x over previous
//
#include <hip/hip_runtime.h>
#include <stdint.h>

#define BB 4
#define SS 2048
#define HIDW 2048
#define NH 16
#define NKV 4
#define DD 128

typedef unsigned short u16;
typedef unsigned long long u64;
typedef unsigned int uint;
typedef __attribute__((ext_vector_type(8))) short bf16x8;
typedef __attribute__((ext_vector_type(4))) float f32x4;
typedef __attribute__((ext_vector_type(2))) float f32x2;
typedef __attribute__((ext_vector_type(2))) __bf16 bf16x2;

__device__ __forceinline__ u16 f2bf1(float f) {
  __bf16 h = (__bf16)f;
  return __builtin_bit_cast(u16, h);
}

__device__ __forceinline__ float bf2f(u16 v) {
  return __uint_as_float((uint)v << 16);
}

// packed f32 pair -> bf16 pair (v_cvt_pk_bf16_f32 on gfx950)
__device__ __forceinline__ uint pkbf(float a, float b) {
  f32x2 v = {a, b};
  bf16x2 h = __builtin_convertvector(v, bf16x2);
  return __builtin_bit_cast(uint, h);
}

__device__ __forceinline__ void gld_lds16(const void* g, void* s) {
  __builtin_amdgcn_global_load_lds(
      (const __attribute__((address_space(1))) void*)g,
      (__attribute__((address_space(3))) void*)(unsigned)(uintptr_t)s,
      16, 0, 0);
}

#define VMCNT(n) asm volatile("s_waitcnt vmcnt(" #n ")" ::: "memory")

__device__ __forceinline__ void barx() {
  asm volatile("" ::: "memory");
  __builtin_amdgcn_s_barrier();
  asm volatile("" ::: "memory");
}

// ---------------- fp32 -> bf16 cast (x) ----------------
__global__ __launch_bounds__(256) void cast_f32_bf16(const float* __restrict__ in,
                                                     u16* __restrict__ out, int n4) {
  int i = blockIdx.x * 256 + threadIdx.x;
  if (i < n4) {
    float4 f = ((const float4*)in)[i];
    uint2 o;
    o.x = pkbf(f.x, f.y);
    o.y = pkbf(f.z, f.w);
    ((uint2*)out)[i] = o;
  }
}

// ---------------- all 4 weight casts in one launch ----------------
__global__ __launch_bounds__(256) void cast_weights(const float* __restrict__ wq,
                                                    const float* __restrict__ wk,
                                                    const float* __restrict__ wv,
                                                    const float* __restrict__ wo,
                                                    u16* __restrict__ wqkvb,
                                                    u16* __restrict__ wob) {
  int i = blockIdx.x * 256 + threadIdx.x;
  const float* src;
  uint2* dst;
  int off;
  if (i < 1048576) {
    src = wq; dst = (uint2*)wqkvb; off = i;
  } else if (i < 1310720) {
    src = wk; dst = (uint2*)(wqkvb + (size_t)2048 * 2048); off = i - 1048576;
  } else if (i < 1572864) {
    src = wv; dst = (uint2*)(wqkvb + (size_t)2560 * 2048); off = i - 1310720;
  } else {
    src = wo; dst = (uint2*)wob; off = i - 1572864;
  }
  float4 f = ((const float4*)src)[off];
  uint2 o;
  o.x = pkbf(f.x, f.y);
  o.y = pkbf(f.z, f.w);
  dst[off] = o;
}

// ---------------- 256x256 8-wave 4-phase pipelined GEMM mainloop ----------------
// LDS bank fix (R6): full (row&7) XOR on 16B block index. Rows are 128B = one
// full bank sweep, so bank = within-row offset only; the old single-bit key
// left each ds_read_b128 on 4 of 8 slots (16 banks idle, 2x serialization).
// New: stored blk = logical_blk ^ (row&7); staging pre-XORs the GLOBAL source
// (linear LDS dest, rule 21), reads XOR with lr&7 (all other row terms are
// multiples of 8). Per instruction: 8 lanes/slot x 8 slots = 8 words/bank
// (optimal), row aliasing 2-way = free.
__device__ __forceinline__ void mm256(const u16* __restrict__ A,
                                      const u16* __restrict__ Bt,
                                      int row0, int col0, f32x4 (&acc)[4][8]) {
  __shared__ u16 S[2][2][16384];
  const int tid = threadIdx.x;
  const int wave = tid >> 6, lane = tid & 63;
  const int lr = lane & 15, lq = lane >> 4;
  const int wr = wave >> 1, wc = wave & 1;

  // staging: thread t covers stored row rs=t>>3, blk=t&7; source k-block
  // pre-XORed so stored blk holds logical blk ^ (rs&7).
  const int sk = (((tid & 7) ^ ((tid >> 3) & 7)) * 8);
  const u16* aS = A + (size_t)(row0 + (tid >> 3)) * 2048 + sk;
  const u16* bS = Bt + (size_t)(col0 + (tid >> 3)) * 2048 + sk;

  const int key = lr & 7;
  const int arow = (wr * 64 + lr) * 128;
  const int brow = (wc * 128 + lr) * 128;

  auto stA = [&](int buf, int h, int k0) {
    char* d = (char*)&S[buf][0][0] + h * 16384 + wave * 1024;
    const u16* s = aS + (size_t)h * 262144 + k0;
    gld_lds16(s, d);
    gld_lds16(s + 131072, d + 8192);
  };
  auto stB = [&](int buf, int h, int k0) {
    char* d = (char*)&S[buf][1][0] + h * 16384 + wave * 1024;
    const u16* s = bS + (size_t)h * 262144 + k0;
    gld_lds16(s, d);
    gld_lds16(s + 131072, d + 8192);
  };

  stA(0, 0, 0);
  stA(0, 1, 0);
  stB(0, 0, 0);
  stB(0, 1, 0);

  for (int t = 0; t < 32; ++t) {
    const int cur = t & 1;
    const char* LA = (const char*)&S[cur][0][0];
    const char* LB = (const char*)&S[cur][1][0];
    const int nk0 = (t + 1) * 64;

    if (t < 31) {
      stA(cur ^ 1, 0, nk0);
      stA(cur ^ 1, 1, nk0);
      VMCNT(4);
    } else {
      VMCNT(0);
    }
    barx();

    bf16x8 a0[2][2], a1[2][2], bq[4][2];
    // ---- ph0 ----
#pragma unroll
    for (int m2 = 0; m2 < 2; ++m2)
#pragma unroll
      for (int kk = 0; kk < 2; ++kk)
        a0[m2][kk] = *(const bf16x8*)(LA + arow + m2 * 2048 + (((kk * 4 + lq) ^ key) << 4));
#pragma unroll
    for (int n = 0; n < 4; ++n)
#pragma unroll
      for (int kk = 0; kk < 2; ++kk)
        bq[n][kk] = *(const bf16x8*)(LB + brow + n * 2048 + (((kk * 4 + lq) ^ key) << 4));
    if (t < 31) stB(cur ^ 1, 0, nk0);
    barx();
    __builtin_amdgcn_s_setprio(1);
#pragma unroll
    for (int kk = 0; kk < 2; ++kk)
#pragma unroll
      for (int m2 = 0; m2 < 2; ++m2)
#pragma unroll
        for (int n = 0; n < 4; ++n)
          acc[m2][n] = __builtin_amdgcn_mfma_f32_16x16x32_bf16(a0[m2][kk], bq[n][kk],
                                                               acc[m2][n], 0, 0, 0);
    __builtin_amdgcn_s_setprio(0);
    barx();

    // ---- ph1 ----
#pragma unroll
    for (int m2 = 0; m2 < 2; ++m2)
#pragma unroll
      for (int kk = 0; kk < 2; ++kk)
        a1[m2][kk] = *(const bf16x8*)(LA + arow + (m2 + 2) * 2048 + (((kk * 4 + lq) ^ key) << 4));
    if (t < 31) stB(cur ^ 1, 1, nk0);
    barx();
    __builtin_amdgcn_s_setprio(1);
#pragma unroll
    for (int kk = 0; kk < 2; ++kk)
#pragma unroll
      for (int m2 = 0; m2 < 2; ++m2)
#pragma unroll
        for (int n = 0; n < 4; ++n)
          acc[m2 + 2][n] = __builtin_amdgcn_mfma_f32_16x16x32_bf16(a1[m2][kk], bq[n][kk],
                                                                   acc[m2 + 2][n], 0, 0, 0);
    __builtin_amdgcn_s_setprio(0);
    barx();

    // ---- ph2 ----
#pragma unroll
    for (int n = 0; n < 4; ++n)
#pragma unroll
      for (int kk = 0; kk < 2; ++kk)
        bq[n][kk] = *(const bf16x8*)(LB + brow + (n + 4) * 2048 + (((kk * 4 + lq) ^ key) << 4));
    barx();
    __builtin_amdgcn_s_setprio(1);
#pragma unroll
    for (int kk = 0; kk < 2; ++kk)
#pragma unroll
      for (int m2 = 0; m2 < 2; ++m2)
#pragma unroll
        for (int n = 0; n < 4; ++n)
          acc[m2 + 2][n + 4] = __builtin_amdgcn_mfma_f32_16x16x32_bf16(
              a1[m2][kk], bq[n][kk], acc[m2 + 2][n + 4], 0, 0, 0);
    __builtin_amdgcn_s_setprio(0);
    barx();

    // ---- ph3 ----
    __builtin_amdgcn_s_setprio(1);
#pragma unroll
    for (int kk = 0; kk < 2; ++kk)
#pragma unroll
      for (int m2 = 0; m2 < 2; ++m2)
#pragma unroll
        for (int n = 0; n < 4; ++n)
          acc[m2][n + 4] = __builtin_amdgcn_mfma_f32_16x16x32_bf16(
              a0[m2][kk], bq[n][kk], acc[m2][n + 4], 0, 0, 0);
    __builtin_amdgcn_s_setprio(0);
    barx();
  }
}

// ---------------- fused QKV GEMM + RoPE + head scatter + V transpose -----------
__global__ __launch_bounds__(512, 2) void gemm_qkv_rope256(const u16* __restrict__ A,
                                                           const u16* __restrict__ Bt,
                                                           const float* __restrict__ cosT,
                                                           const float* __restrict__ sinT,
                                                           u16* __restrict__ qb,
                                                           u16* __restrict__ kb,
                                                           u16* __restrict__ vt) {
  const int bid = blockIdx.x;                 // 384 blocks, 384%8==0
  const int nid = (bid & 7) * 48 + (bid >> 3);  // XCD-chunked, y-major per XCD
  const int bxx = nid % 12, byy = nid / 12;
  const int row0 = byy * 256, col0 = bxx * 256;

  f32x4 acc[4][8] = {};
  mm256(A, Bt, row0, col0, acc);

  const int tid = threadIdx.x;
  const int wave = tid >> 6, lane = tid & 63;
  const int lr = lane & 15, lq = lane >> 4;
  const int wr = wave >> 1, wc = wave & 1;

  const int b_ = row0 >> 11;                 // tile never crosses batch (2048%256==0)
  const int sbase = (row0 & (SS - 1)) + wr * 64;
  const int hsel = bxx * 2 + wc;             // wave covers exactly one 128-wide head

  if (hsel < 20) {
    // q-heads: fold 1/sqrt(D) * log2(e) so flash can use exp2 directly
    const float scale = (hsel < 16) ? 0.12751744416168222f : 1.0f;
    u16* base = (hsel < 16)
                    ? qb + (size_t)(b_ * NH + hsel) * SS * DD
                    : kb + (size_t)(b_ * NKV + (hsel - 16)) * SS * DD;
#pragma unroll
    for (int i = 0; i < 4; i++) {
#pragma unroll
      for (int r = 0; r < 4; r++) {
        int s = sbase + i * 16 + lq * 4 + r;
        const float* cp = cosT + (size_t)s * DD;
        const float* sp = sinT + (size_t)s * DD;
        u16* drow = base + (size_t)s * DD;
#pragma unroll
        for (int j = 0; j < 4; j++) {
          int d = j * 16 + lr;
          float c = cp[d], si = sp[d];
          float x0 = acc[i][j][r] * scale, x1 = acc[i][j + 4][r] * scale;
          drow[d] = f2bf1(x0 * c - x1 * si);
          drow[d + 64] = f2bf1(x1 * c + x0 * si);
        }
      }
    }
  } else {
    const int kv = hsel - 20;
#pragma unroll
    for (int i = 0; i < 4; i++) {
      int s = sbase + i * 16 + lq * 4;
#pragma unroll
      for (int j = 0; j < 8; j++) {
        int d = j * 16 + lr;
        u64 pw = (u64)pkbf(acc[i][j][0], acc[i][j][1]) |
                 ((u64)pkbf(acc[i][j][2], acc[i][j][3]) << 32);
        *(u64*)(vt + (size_t)((b_ * NKV + kv) * DD + d) * SS + s) = pw;
      }
    }
  }
}

// ---------------- out-projection GEMM: out(f32) = ob(bf16) * wob^T --------------
__global__ __launch_bounds__(512, 2) void gemm_out256(const u16* __restrict__ A,
                                                      const u16* __restrict__ Bt,
                                                      float* __restrict__ C) {
  const int bid = blockIdx.x;                 // 256 blocks
  const int nid = (bid & 7) * 32 + (bid >> 3);
  const int bxx = nid & 7, byy = nid >> 3;
  const int row0 = byy * 256, col0 = bxx * 256;

  f32x4 acc[4][8] = {};
  mm256(A, Bt, row0, col0, acc);

  const int tid = threadIdx.x;
  const int wave = tid >> 6, lane = tid & 63;
  const int lr = lane & 15, lq = lane >> 4;
  const int wr = wave >> 1, wc = wave & 1;

#pragma unroll
  for (int i = 0; i < 4; i++) {
    int row = row0 + wr * 64 + i * 16 + lq * 4;
#pragma unroll
    for (int j = 0; j < 8; j++) {
      int col = col0 + wc * 128 + j * 16 + lr;
      float* cp = C + (size_t)row * HIDW + col;
#pragma unroll
      for (int r = 0; r < 4; r++) cp[(size_t)r * HIDW] = acc[i][j][r];
    }
  }
}

// ---------------- transposed flash attention v4 (R4-proven) + exp2 --------------
// Structure byte-identical to R4 (KVB=64, Pt round-trip, 80KB LDS, 2 blk/CU);
// only __expf -> exp2f with log2e pre-folded into Q scale (proven in R5).
__global__ __launch_bounds__(256, 2) void flash_attn(const u16* __restrict__ qb,
                                                     const u16* __restrict__ kb,
                                                     const u16* __restrict__ vt,
                                                     u16* __restrict__ ob) {
  __shared__ u16 Ks[2][64 * 128];  // [kv][d], 16B-blk swizzle ^ (row&15)
  __shared__ u16 Vs[2][128 * 64];  // [d][s],  16B-blk swizzle ^ (row&7)
  __shared__ u16 Pt[128 * 64];     // [q][kv], 16B-blk swizzle ^ (row&7)
  const int tid = threadIdx.x;
  const int wave = tid >> 6, lane = tid & 63;
  const int lr = lane & 15, lq = lane >> 4;

  const int lin = blockIdx.y * 16 + blockIdx.x;
  const int xcd = lin & 7;
  const int slot = lin >> 3;               // 0..127
  const int pr = xcd + ((slot & 1) << 3);  // (b,kvh) id 0..15
  const int b = pr >> 2, kvh = pr & 3;
  const int rest = slot >> 1;              // 0..63
  const int h = kvh * 4 + (rest & 3);
  const int q0 = (rest >> 2) * 128;
  const int bh = b * 16 + h;

  const size_t kbase = (size_t)(b * NKV + kvh) * SS * DD;
  const size_t vbase = (size_t)(b * NKV + kvh) * DD * SS;

  bf16x8 qf[2][4];
#pragma unroll
  for (int nt = 0; nt < 2; nt++) {
    const u16* qrow = qb + ((size_t)bh * SS + q0 + wave * 32 + nt * 16 + lr) * DD + lq * 8;
#pragma unroll
    for (int kk = 0; kk < 4; kk++) qf[nt][kk] = *(const bf16x8*)(qrow + kk * 32);
  }

  f32x4 o_acc[8][2] = {};
  float l_i[2] = {0.0f, 0.0f};

  const int ktrow = tid >> 4;
  const int ktblk = (tid & 15) ^ ktrow;
  const u16* ksrc = kb + kbase + (size_t)ktrow * DD + ktblk * 8;
  const int vtrow = tid >> 3;
  const int vtblk = (tid & 7) ^ (vtrow & 7);
  const u16* vsrc = vt + vbase + (size_t)vtrow * SS + vtblk * 8;

  // prologue: prefetch tile 0 into buffer 0
  {
    char* kd = (char*)(Ks[0]) + wave * 1024;
    char* vd = (char*)(Vs[0]) + wave * 1024;
#pragma unroll
    for (int c = 0; c < 4; c++) {
      gld_lds16(ksrc + (size_t)c * 16 * DD, kd + c * 4096);
      gld_lds16(vsrc + (size_t)c * 32 * SS, vd + c * 4096);
    }
  }

  for (int it = 0; it < SS / 64; it++) {
    __syncthreads();  // drains own prefetch (in flight for a whole compute phase)
    if (it + 1 < SS / 64) {
      int s0 = (it + 1) * 64;
      char* kd = (char*)(Ks[(it + 1) & 1]) + wave * 1024;
      char* vd = (char*)(Vs[(it + 1) & 1]) + wave * 1024;
#pragma unroll
      for (int c = 0; c < 4; c++) {
        gld_lds16(ksrc + (size_t)(s0 + c * 16) * DD, kd + c * 4096);
        gld_lds16(vsrc + s0 + (size_t)c * 32 * SS, vd + c * 4096);
      }
    }
    const u16* K = Ks[it & 1];
    const u16* V = Vs[it & 1];

    f32x4 sc[4][2] = {};
    __builtin_amdgcn_s_setprio(1);
#pragma unroll
    for (int kk = 0; kk < 4; kk++) {
#pragma unroll
      for (int mt = 0; mt < 4; mt++) {
        bf16x8 kf = *(const bf16x8*)(K + (mt * 16 + lr) * 128 + (((kk * 4 + lq) ^ lr) * 8));
#pragma unroll
        for (int nt = 0; nt < 2; nt++)
          sc[mt][nt] = __builtin_amdgcn_mfma_f32_16x16x32_bf16(kf, qf[nt][kk], sc[mt][nt], 0, 0, 0);
      }
    }
    __builtin_amdgcn_s_setprio(0);

#pragma unroll
    for (int nt = 0; nt < 2; nt++) {
      float rs = 0.0f;
#pragma unroll
      for (int mt = 0; mt < 4; mt++)
#pragma unroll
        for (int r = 0; r < 4; r++) {
          float p = __builtin_exp2f(sc[mt][nt][r]);  // log2e folded into Q scale
          sc[mt][nt][r] = p;
          rs += p;
        }
      l_i[nt] += rs;
      int prow = wave * 32 + nt * 16 + lr;
#pragma unroll
      for (int mt = 0; mt < 4; mt++) {
        u64 pw = (u64)pkbf(sc[mt][nt][0], sc[mt][nt][1]) |
                 ((u64)pkbf(sc[mt][nt][2], sc[mt][nt][3]) << 32);
        int bb = (mt * 2 + (lq >> 1)) ^ (lr & 7);
        *(u64*)((char*)Pt + prow * 128 + bb * 16 + (lq & 1) * 8) = pw;
      }
    }

    __builtin_amdgcn_s_setprio(1);
#pragma unroll
    for (int kk2 = 0; kk2 < 2; kk2++) {
      bf16x8 pbf[2];
#pragma unroll
      for (int nt = 0; nt < 2; nt++) {
        int prow = wave * 32 + nt * 16 + lr;
        pbf[nt] = *(const bf16x8*)((char*)Pt + prow * 128 + (((kk2 * 4 + lq) ^ (lr & 7)) * 16));
      }
#pragma unroll
      for (int mt = 0; mt < 8; mt++) {
        bf16x8 vf = *(const bf16x8*)(V + (mt * 16 + lr) * 64 + (((kk2 * 4 + lq) ^ (lr & 7)) * 8));
#pragma unroll
        for (int nt = 0; nt < 2; nt++)
          o_acc[mt][nt] = __builtin_amdgcn_mfma_f32_16x16x32_bf16(vf, pbf[nt], o_acc[mt][nt], 0, 0, 0);
      }
    }
    __builtin_amdgcn_s_setprio(0);
  }

#pragma unroll
  for (int nt = 0; nt < 2; nt++) {
    float l = l_i[nt];
    l += __shfl_xor(l, 16, 64);
    l += __shfl_xor(l, 32, 64);
    float inv = 1.0f / l;
    size_t q = (size_t)q0 + wave * 32 + nt * 16 + lr;
    u16* dst = ob + ((size_t)b * SS + q) * HIDW + h * DD + lq * 4;
#pragma unroll
    for (int mt = 0; mt < 8; mt++) {
      uint2 pk;
      pk.x = pkbf(o_acc[mt][nt][0] * inv, o_acc[mt][nt][1] * inv);
      pk.y = pkbf(o_acc[mt][nt][2] * inv, o_acc[mt][nt][3] * inv);
      *(uint2*)(dst + mt * 16) = pk;
    }
  }
}

extern "C" void kernel_launch(void* const* d_in, const int* in_sizes, int n_in,
                              void* d_out, int out_size, void* d_ws, size_t ws_size,
                              hipStream_t stream) {
  const float* x = (const float*)d_in[0];
  const float* cosT = (const float*)d_in[1];
  const float* sinT = (const float*)d_in[2];
  const float* wq = (const float*)d_in[3];
  const float* wk = (const float*)d_in[4];
  const float* wv = (const float*)d_in[5];
  const float* wo = (const float*)d_in[6];
  float* out = (float*)d_out;

  char* ws = (char*)d_ws;
  size_t off = 0;
  auto alloc = [&](size_t bytes) {
    char* p = ws + off;
    off += (bytes + 255) & ~(size_t)255;
    return p;
  };
  const int M = BB * SS;
  u16* xb = (u16*)alloc((size_t)M * HIDW * 2);
  u16* wqkvb = (u16*)alloc((size_t)3072 * HIDW * 2);  // wq|wk|wv contiguous
  u16* wob = (u16*)alloc((size_t)HIDW * NH * DD * 2);
  u16* qb = (u16*)alloc((size_t)BB * NH * SS * DD * 2);
  u16* kb = (u16*)alloc((size_t)BB * NKV * SS * DD * 2);
  u16* vt = (u16*)alloc((size_t)BB * NKV * DD * SS * 2);
  u16* ob = (u16*)alloc((size_t)M * HIDW * 2);

  cast_f32_bf16<<<(M * HIDW) / 1024, 256, 0, stream>>>(x, xb, (M * HIDW) / 4);
  cast_weights<<<10240, 256, 0, stream>>>(wq, wk, wv, wo, wqkvb, wob);

  gemm_qkv_rope256<<<384, 512, 0, stream>>>(xb, wqkvb, cosT, sinT, qb, kb, vt);

  flash_attn<<<dim3(SS / 128, BB * NH), 256, 0, stream>>>(qb, kb, vt, ob);

  gemm_out256<<<256, 512, 0, stream>>>(ob, wob, out);
}

// Round 7
// 474.518 us; speedup vs baseline: 1.1703x; 1.0410x over previous
//
#include <hip/hip_runtime.h>
#include <stdint.h>

#define BB 4
#define SS 2048
#define HIDW 2048
#define NH 16
#define NKV 4
#define DD 128

typedef unsigned short u16;
typedef unsigned long long u64;
typedef unsigned int uint;
typedef __attribute__((ext_vector_type(8))) short bf16x8;
typedef __attribute__((ext_vector_type(4))) float f32x4;
typedef __attribute__((ext_vector_type(2))) float f32x2;
typedef __attribute__((ext_vector_type(2))) __bf16 bf16x2;

__device__ __forceinline__ u16 f2bf1(float f) {
  __bf16 h = (__bf16)f;
  return __builtin_bit_cast(u16, h);
}

__device__ __forceinline__ float bf2f(u16 v) {
  return __uint_as_float((uint)v << 16);
}

// packed f32 pair -> bf16 pair (v_cvt_pk_bf16_f32 on gfx950)
__device__ __forceinline__ uint pkbf(float a, float b) {
  f32x2 v = {a, b};
  bf16x2 h = __builtin_convertvector(v, bf16x2);
  return __builtin_bit_cast(uint, h);
}

__device__ __forceinline__ void gld_lds16(const void* g, void* s) {
  __builtin_amdgcn_global_load_lds(
      (const __attribute__((address_space(1))) void*)g,
      (__attribute__((address_space(3))) void*)(unsigned)(uintptr_t)s,
      16, 0, 0);
}

#define VMCNT(n) asm volatile("s_waitcnt vmcnt(" #n ")" ::: "memory")

__device__ __forceinline__ void barx() {
  asm volatile("" ::: "memory");
  __builtin_amdgcn_s_barrier();
  asm volatile("" ::: "memory");
}

// ---------------- fp32 -> bf16 cast (x) ----------------
__global__ __launch_bounds__(256) void cast_f32_bf16(const float* __restrict__ in,
                                                     u16* __restrict__ out, int n4) {
  int i = blockIdx.x * 256 + threadIdx.x;
  if (i < n4) {
    float4 f = ((const float4*)in)[i];
    uint2 o;
    o.x = pkbf(f.x, f.y);
    o.y = pkbf(f.z, f.w);
    ((uint2*)out)[i] = o;
  }
}

// ---------------- all 4 weight casts in one launch ----------------
__global__ __launch_bounds__(256) void cast_weights(const float* __restrict__ wq,
                                                    const float* __restrict__ wk,
                                                    const float* __restrict__ wv,
                                                    const float* __restrict__ wo,
                                                    u16* __restrict__ wqkvb,
                                                    u16* __restrict__ wob) {
  int i = blockIdx.x * 256 + threadIdx.x;
  const float* src;
  uint2* dst;
  int off;
  if (i < 1048576) {
    src = wq; dst = (uint2*)wqkvb; off = i;
  } else if (i < 1310720) {
    src = wk; dst = (uint2*)(wqkvb + (size_t)2048 * 2048); off = i - 1048576;
  } else if (i < 1572864) {
    src = wv; dst = (uint2*)(wqkvb + (size_t)2560 * 2048); off = i - 1310720;
  } else {
    src = wo; dst = (uint2*)wob; off = i - 1572864;
  }
  float4 f = ((const float4*)src)[off];
  uint2 o;
  o.x = pkbf(f.x, f.y);
  o.y = pkbf(f.z, f.w);
  dst[off] = o;
}

// ---------------- 256x256 8-wave 4-phase pipelined GEMM mainloop ----------------
// (R6-proven: full (row&7) XOR bank key, both-sides swizzle, ~26us combined win)
__device__ __forceinline__ void mm256(const u16* __restrict__ A,
                                      const u16* __restrict__ Bt,
                                      int row0, int col0, f32x4 (&acc)[4][8]) {
  __shared__ u16 S[2][2][16384];
  const int tid = threadIdx.x;
  const int wave = tid >> 6, lane = tid & 63;
  const int lr = lane & 15, lq = lane >> 4;
  const int wr = wave >> 1, wc = wave & 1;

  // staging: thread t covers stored row rs=t>>3, blk=t&7; source k-block
  // pre-XORed so stored blk holds logical blk ^ (rs&7).
  const int sk = (((tid & 7) ^ ((tid >> 3) & 7)) * 8);
  const u16* aS = A + (size_t)(row0 + (tid >> 3)) * 2048 + sk;
  const u16* bS = Bt + (size_t)(col0 + (tid >> 3)) * 2048 + sk;

  const int key = lr & 7;
  const int arow = (wr * 64 + lr) * 128;
  const int brow = (wc * 128 + lr) * 128;

  auto stA = [&](int buf, int h, int k0) {
    char* d = (char*)&S[buf][0][0] + h * 16384 + wave * 1024;
    const u16* s = aS + (size_t)h * 262144 + k0;
    gld_lds16(s, d);
    gld_lds16(s + 131072, d + 8192);
  };
  auto stB = [&](int buf, int h, int k0) {
    char* d = (char*)&S[buf][1][0] + h * 16384 + wave * 1024;
    const u16* s = bS + (size_t)h * 262144 + k0;
    gld_lds16(s, d);
    gld_lds16(s + 131072, d + 8192);
  };

  stA(0, 0, 0);
  stA(0, 1, 0);
  stB(0, 0, 0);
  stB(0, 1, 0);

  for (int t = 0; t < 32; ++t) {
    const int cur = t & 1;
    const char* LA = (const char*)&S[cur][0][0];
    const char* LB = (const char*)&S[cur][1][0];
    const int nk0 = (t + 1) * 64;

    if (t < 31) {
      stA(cur ^ 1, 0, nk0);
      stA(cur ^ 1, 1, nk0);
      VMCNT(4);
    } else {
      VMCNT(0);
    }
    barx();

    bf16x8 a0[2][2], a1[2][2], bq[4][2];
    // ---- ph0 ----
#pragma unroll
    for (int m2 = 0; m2 < 2; ++m2)
#pragma unroll
      for (int kk = 0; kk < 2; ++kk)
        a0[m2][kk] = *(const bf16x8*)(LA + arow + m2 * 2048 + (((kk * 4 + lq) ^ key) << 4));
#pragma unroll
    for (int n = 0; n < 4; ++n)
#pragma unroll
      for (int kk = 0; kk < 2; ++kk)
        bq[n][kk] = *(const bf16x8*)(LB + brow + n * 2048 + (((kk * 4 + lq) ^ key) << 4));
    if (t < 31) stB(cur ^ 1, 0, nk0);
    barx();
    __builtin_amdgcn_s_setprio(1);
#pragma unroll
    for (int kk = 0; kk < 2; ++kk)
#pragma unroll
      for (int m2 = 0; m2 < 2; ++m2)
#pragma unroll
        for (int n = 0; n < 4; ++n)
          acc[m2][n] = __builtin_amdgcn_mfma_f32_16x16x32_bf16(a0[m2][kk], bq[n][kk],
                                                               acc[m2][n], 0, 0, 0);
    __builtin_amdgcn_s_setprio(0);
    barx();

    // ---- ph1 ----
#pragma unroll
    for (int m2 = 0; m2 < 2; ++m2)
#pragma unroll
      for (int kk = 0; kk < 2; ++kk)
        a1[m2][kk] = *(const bf16x8*)(LA + arow + (m2 + 2) * 2048 + (((kk * 4 + lq) ^ key) << 4));
    if (t < 31) stB(cur ^ 1, 1, nk0);
    barx();
    __builtin_amdgcn_s_setprio(1);
#pragma unroll
    for (int kk = 0; kk < 2; ++kk)
#pragma unroll
      for (int m2 = 0; m2 < 2; ++m2)
#pragma unroll
        for (int n = 0; n < 4; ++n)
          acc[m2 + 2][n] = __builtin_amdgcn_mfma_f32_16x16x32_bf16(a1[m2][kk], bq[n][kk],
                                                                   acc[m2 + 2][n], 0, 0, 0);
    __builtin_amdgcn_s_setprio(0);
    barx();

    // ---- ph2 ----
#pragma unroll
    for (int n = 0; n < 4; ++n)
#pragma unroll
      for (int kk = 0; kk < 2; ++kk)
        bq[n][kk] = *(const bf16x8*)(LB + brow + (n + 4) * 2048 + (((kk * 4 + lq) ^ key) << 4));
    barx();
    __builtin_amdgcn_s_setprio(1);
#pragma unroll
    for (int kk = 0; kk < 2; ++kk)
#pragma unroll
      for (int m2 = 0; m2 < 2; ++m2)
#pragma unroll
        for (int n = 0; n < 4; ++n)
          acc[m2 + 2][n + 4] = __builtin_amdgcn_mfma_f32_16x16x32_bf16(
              a1[m2][kk], bq[n][kk], acc[m2 + 2][n + 4], 0, 0, 0);
    __builtin_amdgcn_s_setprio(0);
    barx();

    // ---- ph3 ----
    __builtin_amdgcn_s_setprio(1);
#pragma unroll
    for (int kk = 0; kk < 2; ++kk)
#pragma unroll
      for (int m2 = 0; m2 < 2; ++m2)
#pragma unroll
        for (int n = 0; n < 4; ++n)
          acc[m2][n + 4] = __builtin_amdgcn_mfma_f32_16x16x32_bf16(
              a0[m2][kk], bq[n][kk], acc[m2][n + 4], 0, 0, 0);
    __builtin_amdgcn_s_setprio(0);
    barx();
  }
}

// ---------------- fused QKV GEMM + RoPE + head scatter + V transpose -----------
__global__ __launch_bounds__(512, 2) void gemm_qkv_rope256(const u16* __restrict__ A,
                                                           const u16* __restrict__ Bt,
                                                           const float* __restrict__ cosT,
                                                           const float* __restrict__ sinT,
                                                           u16* __restrict__ qb,
                                                           u16* __restrict__ kb,
                                                           u16* __restrict__ vt) {
  const int bid = blockIdx.x;                 // 384 blocks, 384%8==0
  const int nid = (bid & 7) * 48 + (bid >> 3);  // XCD-chunked, y-major per XCD
  const int bxx = nid % 12, byy = nid / 12;
  const int row0 = byy * 256, col0 = bxx * 256;

  f32x4 acc[4][8] = {};
  mm256(A, Bt, row0, col0, acc);

  const int tid = threadIdx.x;
  const int wave = tid >> 6, lane = tid & 63;
  const int lr = lane & 15, lq = lane >> 4;
  const int wr = wave >> 1, wc = wave & 1;

  const int b_ = row0 >> 11;                 // tile never crosses batch (2048%256==0)
  const int sbase = (row0 & (SS - 1)) + wr * 64;
  const int hsel = bxx * 2 + wc;             // wave covers exactly one 128-wide head

  if (hsel < 20) {
    const float scale = (hsel < 16) ? 0.08838834764831845f : 1.0f;  // 1/sqrt(D)
    u16* base = (hsel < 16)
                    ? qb + (size_t)(b_ * NH + hsel) * SS * DD
                    : kb + (size_t)(b_ * NKV + (hsel - 16)) * SS * DD;
#pragma unroll
    for (int i = 0; i < 4; i++) {
#pragma unroll
      for (int r = 0; r < 4; r++) {
        int s = sbase + i * 16 + lq * 4 + r;
        const float* cp = cosT + (size_t)s * DD;
        const float* sp = sinT + (size_t)s * DD;
        u16* drow = base + (size_t)s * DD;
#pragma unroll
        for (int j = 0; j < 4; j++) {
          int d = j * 16 + lr;
          float c = cp[d], si = sp[d];
          float x0 = acc[i][j][r] * scale, x1 = acc[i][j + 4][r] * scale;
          drow[d] = f2bf1(x0 * c - x1 * si);
          drow[d + 64] = f2bf1(x1 * c + x0 * si);
        }
      }
    }
  } else {
    const int kv = hsel - 20;
#pragma unroll
    for (int i = 0; i < 4; i++) {
      int s = sbase + i * 16 + lq * 4;
#pragma unroll
      for (int j = 0; j < 8; j++) {
        int d = j * 16 + lr;
        u64 pw = (u64)pkbf(acc[i][j][0], acc[i][j][1]) |
                 ((u64)pkbf(acc[i][j][2], acc[i][j][3]) << 32);
        *(u64*)(vt + (size_t)((b_ * NKV + kv) * DD + d) * SS + s) = pw;
      }
    }
  }
}

// ---------------- out-projection GEMM: out(f32) = ob(bf16) * wob^T --------------
__global__ __launch_bounds__(512, 2) void gemm_out256(const u16* __restrict__ A,
                                                      const u16* __restrict__ Bt,
                                                      float* __restrict__ C) {
  const int bid = blockIdx.x;                 // 256 blocks
  const int nid = (bid & 7) * 32 + (bid >> 3);
  const int bxx = nid & 7, byy = nid >> 3;
  const int row0 = byy * 256, col0 = bxx * 256;

  f32x4 acc[4][8] = {};
  mm256(A, Bt, row0, col0, acc);

  const int tid = threadIdx.x;
  const int wave = tid >> 6, lane = tid & 63;
  const int lr = lane & 15, lq = lane >> 4;
  const int wr = wave >> 1, wc = wave & 1;

#pragma unroll
  for (int i = 0; i < 4; i++) {
    int row = row0 + wr * 64 + i * 16 + lq * 4;
#pragma unroll
    for (int j = 0; j < 8; j++) {
      int col = col0 + wc * 128 + j * 16 + lr;
      float* cp = C + (size_t)row * HIDW + col;
#pragma unroll
      for (int r = 0; r < 4; r++) cp[(size_t)r * HIDW] = acc[i][j][r];
    }
  }
}

// ---------------- transposed flash attention v4 (R4-proven, __expf) -------------
// Byte-exact R4 structure: KVB=64, Pt round-trip, 80KB LDS, 2 blk/CU, __expf
// (fast native v_mul+v_exp_f32; __builtin_exp2f was the PRECISE ocml path and
// cost +28us in R6 — do not use).
__global__ __launch_bounds__(256, 2) void flash_attn(const u16* __restrict__ qb,
                                                     const u16* __restrict__ kb,
                                                     const u16* __restrict__ vt,
                                                     u16* __restrict__ ob) {
  __shared__ u16 Ks[2][64 * 128];  // [kv][d], 16B-blk swizzle ^ (row&15)
  __shared__ u16 Vs[2][128 * 64];  // [d][s],  16B-blk swizzle ^ (row&7)
  __shared__ u16 Pt[128 * 64];     // [q][kv], 16B-blk swizzle ^ (row&7)
  const int tid = threadIdx.x;
  const int wave = tid >> 6, lane = tid & 63;
  const int lr = lane & 15, lq = lane >> 4;

  const int lin = blockIdx.y * 16 + blockIdx.x;
  const int xcd = lin & 7;
  const int slot = lin >> 3;               // 0..127
  const int pr = xcd + ((slot & 1) << 3);  // (b,kvh) id 0..15
  const int b = pr >> 2, kvh = pr & 3;
  const int rest = slot >> 1;              // 0..63
  const int h = kvh * 4 + (rest & 3);
  const int q0 = (rest >> 2) * 128;
  const int bh = b * 16 + h;

  const size_t kbase = (size_t)(b * NKV + kvh) * SS * DD;
  const size_t vbase = (size_t)(b * NKV + kvh) * DD * SS;

  bf16x8 qf[2][4];
#pragma unroll
  for (int nt = 0; nt < 2; nt++) {
    const u16* qrow = qb + ((size_t)bh * SS + q0 + wave * 32 + nt * 16 + lr) * DD + lq * 8;
#pragma unroll
    for (int kk = 0; kk < 4; kk++) qf[nt][kk] = *(const bf16x8*)(qrow + kk * 32);
  }

  f32x4 o_acc[8][2] = {};
  float l_i[2] = {0.0f, 0.0f};

  const int ktrow = tid >> 4;
  const int ktblk = (tid & 15) ^ ktrow;
  const u16* ksrc = kb + kbase + (size_t)ktrow * DD + ktblk * 8;
  const int vtrow = tid >> 3;
  const int vtblk = (tid & 7) ^ (vtrow & 7);
  const u16* vsrc = vt + vbase + (size_t)vtrow * SS + vtblk * 8;

  // prologue: prefetch tile 0 into buffer 0
  {
    char* kd = (char*)(Ks[0]) + wave * 1024;
    char* vd = (char*)(Vs[0]) + wave * 1024;
#pragma unroll
    for (int c = 0; c < 4; c++) {
      gld_lds16(ksrc + (size_t)c * 16 * DD, kd + c * 4096);
      gld_lds16(vsrc + (size_t)c * 32 * SS, vd + c * 4096);
    }
  }

  for (int it = 0; it < SS / 64; it++) {
    __syncthreads();  // drains own prefetch (in flight for a whole compute phase)
    if (it + 1 < SS / 64) {
      int s0 = (it + 1) * 64;
      char* kd = (char*)(Ks[(it + 1) & 1]) + wave * 1024;
      char* vd = (char*)(Vs[(it + 1) & 1]) + wave * 1024;
#pragma unroll
      for (int c = 0; c < 4; c++) {
        gld_lds16(ksrc + (size_t)(s0 + c * 16) * DD, kd + c * 4096);
        gld_lds16(vsrc + s0 + (size_t)c * 32 * SS, vd + c * 4096);
      }
    }
    const u16* K = Ks[it & 1];
    const u16* V = Vs[it & 1];

    f32x4 sc[4][2] = {};
    __builtin_amdgcn_s_setprio(1);
#pragma unroll
    for (int kk = 0; kk < 4; kk++) {
#pragma unroll
      for (int mt = 0; mt < 4; mt++) {
        bf16x8 kf = *(const bf16x8*)(K + (mt * 16 + lr) * 128 + (((kk * 4 + lq) ^ lr) * 8));
#pragma unroll
        for (int nt = 0; nt < 2; nt++)
          sc[mt][nt] = __builtin_amdgcn_mfma_f32_16x16x32_bf16(kf, qf[nt][kk], sc[mt][nt], 0, 0, 0);
      }
    }
    __builtin_amdgcn_s_setprio(0);

#pragma unroll
    for (int nt = 0; nt < 2; nt++) {
      float rs = 0.0f;
#pragma unroll
      for (int mt = 0; mt < 4; mt++)
#pragma unroll
        for (int r = 0; r < 4; r++) {
          float p = __expf(sc[mt][nt][r]);
          sc[mt][nt][r] = p;
          rs += p;
        }
      l_i[nt] += rs;
      int prow = wave * 32 + nt * 16 + lr;
#pragma unroll
      for (int mt = 0; mt < 4; mt++) {
        u64 pw = (u64)pkbf(sc[mt][nt][0], sc[mt][nt][1]) |
                 ((u64)pkbf(sc[mt][nt][2], sc[mt][nt][3]) << 32);
        int bb = (mt * 2 + (lq >> 1)) ^ (lr & 7);
        *(u64*)((char*)Pt + prow * 128 + bb * 16 + (lq & 1) * 8) = pw;
      }
    }

    __builtin_amdgcn_s_setprio(1);
#pragma unroll
    for (int kk2 = 0; kk2 < 2; kk2++) {
      bf16x8 pbf[2];
#pragma unroll
      for (int nt = 0; nt < 2; nt++) {
        int prow = wave * 32 + nt * 16 + lr;
        pbf[nt] = *(const bf16x8*)((char*)Pt + prow * 128 + (((kk2 * 4 + lq) ^ (lr & 7)) * 16));
      }
#pragma unroll
      for (int mt = 0; mt < 8; mt++) {
        bf16x8 vf = *(const bf16x8*)(V + (mt * 16 + lr) * 64 + (((kk2 * 4 + lq) ^ (lr & 7)) * 8));
#pragma unroll
        for (int nt = 0; nt < 2; nt++)
          o_acc[mt][nt] = __builtin_amdgcn_mfma_f32_16x16x32_bf16(vf, pbf[nt], o_acc[mt][nt], 0, 0, 0);
      }
    }
    __builtin_amdgcn_s_setprio(0);
  }

#pragma unroll
  for (int nt = 0; nt < 2; nt++) {
    float l = l_i[nt];
    l += __shfl_xor(l, 16, 64);
    l += __shfl_xor(l, 32, 64);
    float inv = 1.0f / l;
    size_t q = (size_t)q0 + wave * 32 + nt * 16 + lr;
    u16* dst = ob + ((size_t)b * SS + q) * HIDW + h * DD + lq * 4;
#pragma unroll
    for (int mt = 0; mt < 8; mt++) {
      uint2 pk;
      pk.x = pkbf(o_acc[mt][nt][0] * inv, o_acc[mt][nt][1] * inv);
      pk.y = pkbf(o_acc[mt][nt][2] * inv, o_acc[mt][nt][3] * inv);
      *(uint2*)(dst + mt * 16) = pk;
    }
  }
}

extern "C" void kernel_launch(void* const* d_in, const int* in_sizes, int n_in,
                              void* d_out, int out_size, void* d_ws, size_t ws_size,
                              hipStream_t stream) {
  const float* x = (const float*)d_in[0];
  const float* cosT = (const float*)d_in[1];
  const float* sinT = (const float*)d_in[2];
  const float* wq = (const float*)d_in[3];
  const float* wk = (const float*)d_in[4];
  const float* wv = (const float*)d_in[5];
  const float* wo = (const float*)d_in[6];
  float* out = (float*)d_out;

  char* ws = (char*)d_ws;
  size_t off = 0;
  auto alloc = [&](size_t bytes) {
    char* p = ws + off;
    off += (bytes + 255) & ~(size_t)255;
    return p;
  };
  const int M = BB * SS;
  u16* xb = (u16*)alloc((size_t)M * HIDW * 2);
  u16* wqkvb = (u16*)alloc((size_t)3072 * HIDW * 2);  // wq|wk|wv contiguous
  u16* wob = (u16*)alloc((size_t)HIDW * NH * DD * 2);
  u16* qb = (u16*)alloc((size_t)BB * NH * SS * DD * 2);
  u16* kb = (u16*)alloc((size_t)BB * NKV * SS * DD * 2);
  u16* vt = (u16*)alloc((size_t)BB * NKV * DD * SS * 2);
  u16* ob = (u16*)alloc((size_t)M * HIDW * 2);

  cast_f32_bf16<<<(M * HIDW) / 1024, 256, 0, stream>>>(x, xb, (M * HIDW) / 4);
  cast_weights<<<10240, 256, 0, stream>>>(wq, wk, wv, wo, wqkvb, wob);

  gemm_qkv_rope256<<<384, 512, 0, stream>>>(xb, wqkvb, cosT, sinT, qb, kb, vt);

  flash_attn<<<dim3(SS / 128, BB * NH), 256, 0, stream>>>(qb, kb, vt, ob);

  gemm_out256<<<256, 512, 0, stream>>>(ob, wob, out);
}

// Round 9
// 474.194 us; speedup vs baseline: 1.1711x; 1.0007x over previous
//
#include <hip/hip_runtime.h>
#include <stdint.h>

#define BB 4
#define SS 2048
#define HIDW 2048
#define NH 16
#define NKV 4
#define DD 128

typedef unsigned short u16;
typedef unsigned long long u64;
typedef unsigned int uint;
typedef __attribute__((ext_vector_type(8))) short bf16x8;
typedef __attribute__((ext_vector_type(4))) float f32x4;
typedef __attribute__((ext_vector_type(2))) float f32x2;
typedef __attribute__((ext_vector_type(2))) __bf16 bf16x2;

__device__ __forceinline__ u16 f2bf1(float f) {
  __bf16 h = (__bf16)f;
  return __builtin_bit_cast(u16, h);
}

__device__ __forceinline__ float bf2f(u16 v) {
  return __uint_as_float((uint)v << 16);
}

// packed f32 pair -> bf16 pair (v_cvt_pk_bf16_f32 on gfx950)
__device__ __forceinline__ uint pkbf(float a, float b) {
  f32x2 v = {a, b};
  bf16x2 h = __builtin_convertvector(v, bf16x2);
  return __builtin_bit_cast(uint, h);
}

__device__ __forceinline__ void gld_lds16(const void* g, void* s) {
  __builtin_amdgcn_global_load_lds(
      (const __attribute__((address_space(1))) void*)g,
      (__attribute__((address_space(3))) void*)(unsigned)(uintptr_t)s,
      16, 0, 0);
}

#define VMCNT(n) asm volatile("s_waitcnt vmcnt(" #n ")" ::: "memory")

__device__ __forceinline__ void barx() {
  asm volatile("" ::: "memory");
  __builtin_amdgcn_s_barrier();
  asm volatile("" ::: "memory");
}

// ---------------- all input casts in one launch (x + 4 weights) ----------------
// (proven passing in R1)
__global__ __launch_bounds__(256) void cast_all(const float* __restrict__ x,
                                                const float* __restrict__ wq,
                                                const float* __restrict__ wk,
                                                const float* __restrict__ wv,
                                                const float* __restrict__ wo,
                                                u16* __restrict__ xb,
                                                u16* __restrict__ wqkvb,
                                                u16* __restrict__ wob) {
  int i = blockIdx.x * 256 + threadIdx.x;
  const float* src;
  uint2* dst;
  int off;
  if (i < 4194304) {
    src = x; dst = (uint2*)xb; off = i;
  } else if (i < 5242880) {
    src = wq; dst = (uint2*)wqkvb; off = i - 4194304;
  } else if (i < 5505024) {
    src = wk; dst = (uint2*)(wqkvb + (size_t)2048 * 2048); off = i - 5242880;
  } else if (i < 5767168) {
    src = wv; dst = (uint2*)(wqkvb + (size_t)2560 * 2048); off = i - 5505024;
  } else {
    src = wo; dst = (uint2*)wob; off = i - 5767168;
  }
  float4 f = ((const float4*)src)[off];
  uint2 o;
  o.x = pkbf(f.x, f.y);
  o.y = pkbf(f.z, f.w);
  dst[off] = o;
}

// ---------------- 256x256 8-wave 4-phase pipelined GEMM mainloop ----------------
// (R6/R7-proven: full (row&7) XOR bank key, both-sides swizzle)
__device__ __forceinline__ void mm256(const u16* __restrict__ A,
                                      const u16* __restrict__ Bt,
                                      int row0, int col0, f32x4 (&acc)[4][8]) {
  __shared__ u16 S[2][2][16384];
  const int tid = threadIdx.x;
  const int wave = tid >> 6, lane = tid & 63;
  const int lr = lane & 15, lq = lane >> 4;
  const int wr = wave >> 1, wc = wave & 1;

  const int sk = (((tid & 7) ^ ((tid >> 3) & 7)) * 8);
  const u16* aS = A + (size_t)(row0 + (tid >> 3)) * 2048 + sk;
  const u16* bS = Bt + (size_t)(col0 + (tid >> 3)) * 2048 + sk;

  const int key = lr & 7;
  const int arow = (wr * 64 + lr) * 128;
  const int brow = (wc * 128 + lr) * 128;

  auto stA = [&](int buf, int h, int k0) {
    char* d = (char*)&S[buf][0][0] + h * 16384 + wave * 1024;
    const u16* s = aS + (size_t)h * 262144 + k0;
    gld_lds16(s, d);
    gld_lds16(s + 131072, d + 8192);
  };
  auto stB = [&](int buf, int h, int k0) {
    char* d = (char*)&S[buf][1][0] + h * 16384 + wave * 1024;
    const u16* s = bS + (size_t)h * 262144 + k0;
    gld_lds16(s, d);
    gld_lds16(s + 131072, d + 8192);
  };

  stA(0, 0, 0);
  stA(0, 1, 0);
  stB(0, 0, 0);
  stB(0, 1, 0);

  for (int t = 0; t < 32; ++t) {
    const int cur = t & 1;
    const char* LA = (const char*)&S[cur][0][0];
    const char* LB = (const char*)&S[cur][1][0];
    const int nk0 = (t + 1) * 64;

    if (t < 31) {
      stA(cur ^ 1, 0, nk0);
      stA(cur ^ 1, 1, nk0);
      VMCNT(4);
    } else {
      VMCNT(0);
    }
    barx();

    bf16x8 a0[2][2], a1[2][2], bq[4][2];
    // ---- ph0 ----
#pragma unroll
    for (int m2 = 0; m2 < 2; ++m2)
#pragma unroll
      for (int kk = 0; kk < 2; ++kk)
        a0[m2][kk] = *(const bf16x8*)(LA + arow + m2 * 2048 + (((kk * 4 + lq) ^ key) << 4));
#pragma unroll
    for (int n = 0; n < 4; ++n)
#pragma unroll
      for (int kk = 0; kk < 2; ++kk)
        bq[n][kk] = *(const bf16x8*)(LB + brow + n * 2048 + (((kk * 4 + lq) ^ key) << 4));
    if (t < 31) stB(cur ^ 1, 0, nk0);
    barx();
    __builtin_amdgcn_s_setprio(1);
#pragma unroll
    for (int kk = 0; kk < 2; ++kk)
#pragma unroll
      for (int m2 = 0; m2 < 2; ++m2)
#pragma unroll
        for (int n = 0; n < 4; ++n)
          acc[m2][n] = __builtin_amdgcn_mfma_f32_16x16x32_bf16(a0[m2][kk], bq[n][kk],
                                                               acc[m2][n], 0, 0, 0);
    __builtin_amdgcn_s_setprio(0);
    barx();

    // ---- ph1 ----
#pragma unroll
    for (int m2 = 0; m2 < 2; ++m2)
#pragma unroll
      for (int kk = 0; kk < 2; ++kk)
        a1[m2][kk] = *(const bf16x8*)(LA + arow + (m2 + 2) * 2048 + (((kk * 4 + lq) ^ key) << 4));
    if (t < 31) stB(cur ^ 1, 1, nk0);
    barx();
    __builtin_amdgcn_s_setprio(1);
#pragma unroll
    for (int kk = 0; kk < 2; ++kk)
#pragma unroll
      for (int m2 = 0; m2 < 2; ++m2)
#pragma unroll
        for (int n = 0; n < 4; ++n)
          acc[m2 + 2][n] = __builtin_amdgcn_mfma_f32_16x16x32_bf16(a1[m2][kk], bq[n][kk],
                                                                   acc[m2 + 2][n], 0, 0, 0);
    __builtin_amdgcn_s_setprio(0);
    barx();

    // ---- ph2 ----
#pragma unroll
    for (int n = 0; n < 4; ++n)
#pragma unroll
      for (int kk = 0; kk < 2; ++kk)
        bq[n][kk] = *(const bf16x8*)(LB + brow + (n + 4) * 2048 + (((kk * 4 + lq) ^ key) << 4));
    barx();
    __builtin_amdgcn_s_setprio(1);
#pragma unroll
    for (int kk = 0; kk < 2; ++kk)
#pragma unroll
      for (int m2 = 0; m2 < 2; ++m2)
#pragma unroll
        for (int n = 0; n < 4; ++n)
          acc[m2 + 2][n + 4] = __builtin_amdgcn_mfma_f32_16x16x32_bf16(
              a1[m2][kk], bq[n][kk], acc[m2 + 2][n + 4], 0, 0, 0);
    __builtin_amdgcn_s_setprio(0);
    barx();

    // ---- ph3 ----
    __builtin_amdgcn_s_setprio(1);
#pragma unroll
    for (int kk = 0; kk < 2; ++kk)
#pragma unroll
      for (int m2 = 0; m2 < 2; ++m2)
#pragma unroll
        for (int n = 0; n < 4; ++n)
          acc[m2][n + 4] = __builtin_amdgcn_mfma_f32_16x16x32_bf16(
              a0[m2][kk], bq[n][kk], acc[m2][n + 4], 0, 0, 0);
    __builtin_amdgcn_s_setprio(0);
    barx();
  }
}

// ---------------- fused QKV GEMM + RoPE + head scatter + V transpose -----------
// (R7-proven 256x256 / 384-block version; the 256x128 / 768-block rewrite
// failed correctness twice-unexplained territory and is abandoned)
__global__ __launch_bounds__(512, 2) void gemm_qkv_rope256(const u16* __restrict__ A,
                                                           const u16* __restrict__ Bt,
                                                           const float* __restrict__ cosT,
                                                           const float* __restrict__ sinT,
                                                           u16* __restrict__ qb,
                                                           u16* __restrict__ kb,
                                                           u16* __restrict__ vt) {
  const int bid = blockIdx.x;                 // 384 blocks, 384%8==0
  const int nid = (bid & 7) * 48 + (bid >> 3);  // XCD-chunked, y-major per XCD
  const int bxx = nid % 12, byy = nid / 12;
  const int row0 = byy * 256, col0 = bxx * 256;

  f32x4 acc[4][8] = {};
  mm256(A, Bt, row0, col0, acc);

  const int tid = threadIdx.x;
  const int wave = tid >> 6, lane = tid & 63;
  const int lr = lane & 15, lq = lane >> 4;
  const int wr = wave >> 1, wc = wave & 1;

  const int b_ = row0 >> 11;                 // tile never crosses batch (2048%256==0)
  const int sbase = (row0 & (SS - 1)) + wr * 64;
  const int hsel = bxx * 2 + wc;             // wave covers exactly one 128-wide head

  if (hsel < 20) {
    const float scale = (hsel < 16) ? 0.08838834764831845f : 1.0f;  // 1/sqrt(D)
    u16* base = (hsel < 16)
                    ? qb + (size_t)(b_ * NH + hsel) * SS * DD
                    : kb + (size_t)(b_ * NKV + (hsel - 16)) * SS * DD;
#pragma unroll
    for (int i = 0; i < 4; i++) {
#pragma unroll
      for (int r = 0; r < 4; r++) {
        int s = sbase + i * 16 + lq * 4 + r;
        const float* cp = cosT + (size_t)s * DD;
        const float* sp = sinT + (size_t)s * DD;
        u16* drow = base + (size_t)s * DD;
#pragma unroll
        for (int j = 0; j < 4; j++) {
          int d = j * 16 + lr;
          float c = cp[d], si = sp[d];
          float x0 = acc[i][j][r] * scale, x1 = acc[i][j + 4][r] * scale;
          drow[d] = f2bf1(x0 * c - x1 * si);
          drow[d + 64] = f2bf1(x1 * c + x0 * si);
        }
      }
    }
  } else {
    const int kv = hsel - 20;
#pragma unroll
    for (int i = 0; i < 4; i++) {
      int s = sbase + i * 16 + lq * 4;
#pragma unroll
      for (int j = 0; j < 8; j++) {
        int d = j * 16 + lr;
        u64 pw = (u64)pkbf(acc[i][j][0], acc[i][j][1]) |
                 ((u64)pkbf(acc[i][j][2], acc[i][j][3]) << 32);
        *(u64*)(vt + (size_t)((b_ * NKV + kv) * DD + d) * SS + s) = pw;
      }
    }
  }
}

// ---------------- out-projection GEMM: out(f32) = ob(bf16) * wob^T --------------
__global__ __launch_bounds__(512, 2) void gemm_out256(const u16* __restrict__ A,
                                                      const u16* __restrict__ Bt,
                                                      float* __restrict__ C) {
  const int bid = blockIdx.x;                 // 256 blocks = 1 full round
  const int nid = (bid & 7) * 32 + (bid >> 3);
  const int bxx = nid & 7, byy = nid >> 3;
  const int row0 = byy * 256, col0 = bxx * 256;

  f32x4 acc[4][8] = {};
  mm256(A, Bt, row0, col0, acc);

  const int tid = threadIdx.x;
  const int wave = tid >> 6, lane = tid & 63;
  const int lr = lane & 15, lq = lane >> 4;
  const int wr = wave >> 1, wc = wave & 1;

#pragma unroll
  for (int i = 0; i < 4; i++) {
    int row = row0 + wr * 64 + i * 16 + lq * 4;
#pragma unroll
    for (int j = 0; j < 8; j++) {
      int col = col0 + wc * 128 + j * 16 + lr;
      float* cp = C + (size_t)row * HIDW + col;
#pragma unroll
      for (int r = 0; r < 4; r++) cp[(size_t)r * HIDW] = acc[i][j][r];
    }
  }
}

// ---------------- transposed flash attention v4 (R4/R7-proven, __expf) ----------
// KVB=64, Pt round-trip, 80KB LDS, 2 blk/CU, __expf (fast native path;
// __builtin_exp2f is the PRECISE ocml path and cost +28us in R6 — do not use).
__global__ __launch_bounds__(256, 2) void flash_attn(const u16* __restrict__ qb,
                                                     const u16* __restrict__ kb,
                                                     const u16* __restrict__ vt,
                                                     u16* __restrict__ ob) {
  __shared__ u16 Ks[2][64 * 128];  // [kv][d], 16B-blk swizzle ^ (row&15)
  __shared__ u16 Vs[2][128 * 64];  // [d][s],  16B-blk swizzle ^ (row&7)
  __shared__ u16 Pt[128 * 64];     // [q][kv], 16B-blk swizzle ^ (row&7)
  const int tid = threadIdx.x;
  const int wave = tid >> 6, lane = tid & 63;
  const int lr = lane & 15, lq = lane >> 4;

  const int lin = blockIdx.y * 16 + blockIdx.x;
  const int xcd = lin & 7;
  const int slot = lin >> 3;               // 0..127
  const int pr = xcd + ((slot & 1) << 3);  // (b,kvh) id 0..15
  const int b = pr >> 2, kvh = pr & 3;
  const int rest = slot >> 1;              // 0..63
  const int h = kvh * 4 + (rest & 3);
  const int q0 = (rest >> 2) * 128;
  const int bh = b * 16 + h;

  const size_t kbase = (size_t)(b * NKV + kvh) * SS * DD;
  const size_t vbase = (size_t)(b * NKV + kvh) * DD * SS;

  bf16x8 qf[2][4];
#pragma unroll
  for (int nt = 0; nt < 2; nt++) {
    const u16* qrow = qb + ((size_t)bh * SS + q0 + wave * 32 + nt * 16 + lr) * DD + lq * 8;
#pragma unroll
    for (int kk = 0; kk < 4; kk++) qf[nt][kk] = *(const bf16x8*)(qrow + kk * 32);
  }

  f32x4 o_acc[8][2] = {};
  float l_i[2] = {0.0f, 0.0f};

  const int ktrow = tid >> 4;
  const int ktblk = (tid & 15) ^ ktrow;
  const u16* ksrc = kb + kbase + (size_t)ktrow * DD + ktblk * 8;
  const int vtrow = tid >> 3;
  const int vtblk = (tid & 7) ^ (vtrow & 7);
  const u16* vsrc = vt + vbase + (size_t)vtrow * SS + vtblk * 8;

  // prologue: prefetch tile 0 into buffer 0
  {
    char* kd = (char*)(Ks[0]) + wave * 1024;
    char* vd = (char*)(Vs[0]) + wave * 1024;
#pragma unroll
    for (int c = 0; c < 4; c++) {
      gld_lds16(ksrc + (size_t)c * 16 * DD, kd + c * 4096);
      gld_lds16(vsrc + (size_t)c * 32 * SS, vd + c * 4096);
    }
  }

  for (int it = 0; it < SS / 64; it++) {
    __syncthreads();  // drains own prefetch (in flight for a whole compute phase)
    if (it + 1 < SS / 64) {
      int s0 = (it + 1) * 64;
      char* kd = (char*)(Ks[(it + 1) & 1]) + wave * 1024;
      char* vd = (char*)(Vs[(it + 1) & 1]) + wave * 1024;
#pragma unroll
      for (int c = 0; c < 4; c++) {
        gld_lds16(ksrc + (size_t)(s0 + c * 16) * DD, kd + c * 4096);
        gld_lds16(vsrc + s0 + (size_t)c * 32 * SS, vd + c * 4096);
      }
    }
    const u16* K = Ks[it & 1];
    const u16* V = Vs[it & 1];

    f32x4 sc[4][2] = {};
    __builtin_amdgcn_s_setprio(1);
#pragma unroll
    for (int kk = 0; kk < 4; kk++) {
#pragma unroll
      for (int mt = 0; mt < 4; mt++) {
        bf16x8 kf = *(const bf16x8*)(K + (mt * 16 + lr) * 128 + (((kk * 4 + lq) ^ lr) * 8));
#pragma unroll
        for (int nt = 0; nt < 2; nt++)
          sc[mt][nt] = __builtin_amdgcn_mfma_f32_16x16x32_bf16(kf, qf[nt][kk], sc[mt][nt], 0, 0, 0);
      }
    }
    __builtin_amdgcn_s_setprio(0);

#pragma unroll
    for (int nt = 0; nt < 2; nt++) {
      float rs = 0.0f;
#pragma unroll
      for (int mt = 0; mt < 4; mt++)
#pragma unroll
        for (int r = 0; r < 4; r++) {
          float p = __expf(sc[mt][nt][r]);
          sc[mt][nt][r] = p;
          rs += p;
        }
      l_i[nt] += rs;
      int prow = wave * 32 + nt * 16 + lr;
#pragma unroll
      for (int mt = 0; mt < 4; mt++) {
        u64 pw = (u64)pkbf(sc[mt][nt][0], sc[mt][nt][1]) |
                 ((u64)pkbf(sc[mt][nt][2], sc[mt][nt][3]) << 32);
        int bb = (mt * 2 + (lq >> 1)) ^ (lr & 7);
        *(u64*)((char*)Pt + prow * 128 + bb * 16 + (lq & 1) * 8) = pw;
      }
    }

    __builtin_amdgcn_s_setprio(1);
#pragma unroll
    for (int kk2 = 0; kk2 < 2; kk2++) {
      bf16x8 pbf[2];
#pragma unroll
      for (int nt = 0; nt < 2; nt++) {
        int prow = wave * 32 + nt * 16 + lr;
        pbf[nt] = *(const bf16x8*)((char*)Pt + prow * 128 + (((kk2 * 4 + lq) ^ (lr & 7)) * 16));
      }
#pragma unroll
      for (int mt = 0; mt < 8; mt++) {
        bf16x8 vf = *(const bf16x8*)(V + (mt * 16 + lr) * 64 + (((kk2 * 4 + lq) ^ (lr & 7)) * 8));
#pragma unroll
        for (int nt = 0; nt < 2; nt++)
          o_acc[mt][nt] = __builtin_amdgcn_mfma_f32_16x16x32_bf16(vf, pbf[nt], o_acc[mt][nt], 0, 0, 0);
      }
    }
    __builtin_amdgcn_s_setprio(0);
  }

#pragma unroll
  for (int nt = 0; nt < 2; nt++) {
    float l = l_i[nt];
    l += __shfl_xor(l, 16, 64);
    l += __shfl_xor(l, 32, 64);
    float inv = 1.0f / l;
    size_t q = (size_t)q0 + wave * 32 + nt * 16 + lr;
    u16* dst = ob + ((size_t)b * SS + q) * HIDW + h * DD + lq * 4;
#pragma unroll
    for (int mt = 0; mt < 8; mt++) {
      uint2 pk;
      pk.x = pkbf(o_acc[mt][nt][0] * inv, o_acc[mt][nt][1] * inv);
      pk.y = pkbf(o_acc[mt][nt][2] * inv, o_acc[mt][nt][3] * inv);
      *(uint2*)(dst + mt * 16) = pk;
    }
  }
}

extern "C" void kernel_launch(void* const* d_in, const int* in_sizes, int n_in,
                              void* d_out, int out_size, void* d_ws, size_t ws_size,
                              hipStream_t stream) {
  const float* x = (const float*)d_in[0];
  const float* cosT = (const float*)d_in[1];
  const float* sinT = (const float*)d_in[2];
  const float* wq = (const float*)d_in[3];
  const float* wk = (const float*)d_in[4];
  const float* wv = (const float*)d_in[5];
  const float* wo = (const float*)d_in[6];
  float* out = (float*)d_out;

  char* ws = (char*)d_ws;
  size_t off = 0;
  auto alloc = [&](size_t bytes) {
    char* p = ws + off;
    off += (bytes + 255) & ~(size_t)255;
    return p;
  };
  const int M = BB * SS;
  u16* xb = (u16*)alloc((size_t)M * HIDW * 2);
  u16* wqkvb = (u16*)alloc((size_t)3072 * HIDW * 2);  // wq|wk|wv contiguous
  u16* wob = (u16*)alloc((size_t)HIDW * NH * DD * 2);
  u16* qb = (u16*)alloc((size_t)BB * NH * SS * DD * 2);
  u16* kb = (u16*)alloc((size_t)BB * NKV * SS * DD * 2);
  u16* vt = (u16*)alloc((size_t)BB * NKV * DD * SS * 2);
  u16* ob = (u16*)alloc((size_t)M * HIDW * 2);

  cast_all<<<26624, 256, 0, stream>>>(x, wq, wk, wv, wo, xb, wqkvb, wob);

  gemm_qkv_rope256<<<384, 512, 0, stream>>>(xb, wqkvb, cosT, sinT, qb, kb, vt);

  flash_attn<<<dim3(SS / 128, BB * NH), 256, 0, stream>>>(qb, kb, vt, ob);

  gemm_out256<<<256, 512, 0, stream>>>(ob, wob, out);
}